// Round 4
// baseline (42.881 us; speedup 1.0000x reference)
//
#include <hip/hip_runtime.h>
#include <math.h>

#define NN 1024
#define NBB 16
#define NP 256
#define TT 80
#define EPS_LEN 1e-9f
#define EPS_DD 1e-12f

__device__ __forceinline__ float frcp(float x){ return __builtin_amdgcn_rcpf(x); }
__device__ __forceinline__ float fsq(float x){ return __builtin_amdgcn_sqrtf(x); }

// Wave-synchronous LDS fence (LDS partitioned per wave; no __syncthreads).
__device__ __forceinline__ void lds_fence() {
  __builtin_amdgcn_wave_barrier();
  asm volatile("s_waitcnt lgkmcnt(0)" ::: "memory");
  __builtin_amdgcn_wave_barrier();
}

// n_valid, wave-wide. Mask layout auto-detect: byte[1] of buffer != 0 -> bool
// bytes (mask[0][0][1] true since lengths>=2); int32 layout -> that byte is 0.
__device__ __forceinline__ int wave_nv(const void* mask, size_t base, int lane) {
  bool as_byte = ((const unsigned char*)mask)[1] != 0;
  int nv = 0;
  if (as_byte) {
    uchar4 v = ((const uchar4*)((const unsigned char*)mask + base))[lane];
    nv += __popcll(__ballot(v.x != 0));
    nv += __popcll(__ballot(v.y != 0));
    nv += __popcll(__ballot(v.z != 0));
    nv += __popcll(__ballot(v.w != 0));
  } else {
    int4 v = ((const int4*)((const int*)mask + base))[lane];
    nv += __popcll(__ballot(v.x != 0));
    nv += __popcll(__ballot(v.y != 0));
    nv += __popcll(__ballot(v.z != 0));
    nv += __popcll(__ballot(v.w != 0));
  }
  return nv;
}

struct SegOut {
  float cpre[4];
  float run;
  float bdf, btf; int bjf;   // first-min (fwd entry)
  float bdl, btl; int bjl;   // last-min  (rev entry)
};

// Per-candidate segment pass: load 256 pts (4/lane), stage to LDS (b128),
// compute seg lengths + projection of pos[0] + per-lane argmin state.
__device__ __forceinline__ void seg_pass(const float4* __restrict__ p4, int lane, int nv,
                                         float p0x, float p0y, float p0z,
                                         float* __restrict__ px, float* __restrict__ py,
                                         float* __restrict__ pz, SegOut& R) {
  const int j0 = lane * 4;
  float4 A = p4[lane*3+0], B = p4[lane*3+1], C = p4[lane*3+2];
  float x[5], y[5], z[5];
  x[0]=A.x; y[0]=A.y; z[0]=A.z;
  x[1]=A.w; y[1]=B.x; z[1]=B.y;
  x[2]=B.z; y[2]=B.w; z[2]=C.x;
  x[3]=C.y; y[3]=C.z; z[3]=C.w;
  x[4]=__shfl_down(x[0],1,64); y[4]=__shfl_down(y[0],1,64); z[4]=__shfl_down(z[0],1,64);
  ((float4*)px)[lane] = make_float4(x[0],x[1],x[2],x[3]);
  ((float4*)py)[lane] = make_float4(y[0],y[1],y[2],y[3]);
  ((float4*)pz)[lane] = make_float4(z[0],z[1],z[2],z[3]);
  float run = 0.f;
  R.bdf=INFINITY; R.btf=0.f; R.bjf=j0;
  R.bdl=INFINITY; R.btl=0.f; R.bjl=j0;
  #pragma unroll
  for (int k=0;k<4;k++){
    bool valid = (j0+k) < nv-1;
    float vx=x[k+1]-x[k], vy=y[k+1]-y[k], vz=z[k+1]-z[k];
    float n2 = vx*vx+vy*vy+vz*vz;
    float sl = valid ? fmaxf(fsq(n2), EPS_LEN) : 0.f;
    float t = ((p0x-x[k])*vx+(p0y-y[k])*vy+(p0z-z[k])*vz) * frcp(fmaxf(n2,EPS_DD));
    t = fminf(fmaxf(t,0.f),1.f);
    float qx=x[k]+t*vx, qy=y[k]+t*vy, qz=z[k]+t*vz;
    float dx=p0x-qx, dy=p0y-qy, dz=p0z-qz;
    float d2 = valid ? (dx*dx+dy*dy+dz*dz) : INFINITY;
    if (d2 <  R.bdf){R.bdf=d2; R.bjf=j0+k; R.btf=t;}
    if (d2 <= R.bdl){R.bdl=d2; R.bjl=j0+k; R.btl=t;}
    run += sl; R.cpre[k]=run;
  }
  R.run = run;
}

// K2: one wave per candidate PAIR (same n, boundaries 2b,2b+1), both dirs each.
// Two independent dependency chains per wave -> latency overlap (ILP-2).
__global__ __launch_bounds__(256, 4)
void fused_cost_dual(const float* __restrict__ traj, const float* __restrict__ rp,
                     const void* __restrict__ mask, const float* __restrict__ tcs,
                     float* __restrict__ cost) {
  __shared__ float s_px[4][2*NP], s_py[4][2*NP], s_pz[4][2*NP], s_cs[4][2*NP];
  const int wid = threadIdx.x>>6, lane = threadIdx.x&63;
  const int pair = blockIdx.x*4 + wid;          // 0..8191
  const int n = pair >> 3;
  const size_t nbA = (size_t)n*NBB + ((pair&7)<<1);
  const float* pos = traj + (size_t)n*TT*3;
  const float* tc  = tcs  + (size_t)n*TT;
  float p0x=pos[0], p0y=pos[1], p0z=pos[2];

  int nvAr = wave_nv(mask, nbA*NP, lane);
  int nvBr = wave_nv(mask, (nbA+1)*NP, lane);
  int nvA = max(nvAr,2), nvB = max(nvBr,2);   // data guarantees >=2; clamp for safety

  float* pxw = s_px[wid]; float* pyw = s_py[wid];
  float* pzw = s_pz[wid]; float* csw = s_cs[wid];
  SegOut RA, RB;
  seg_pass((const float4*)(rp + nbA*NP*3),     lane, nvA, p0x,p0y,p0z, pxw,    pyw,    pzw,    RA);
  seg_pass((const float4*)(rp + (nbA+1)*NP*3), lane, nvB, p0x,p0y,p0z, pxw+NP, pyw+NP, pzw+NP, RB);

  // interleaved exclusive scans
  float incA=RA.run, incB=RB.run;
  #pragma unroll
  for (int d=1; d<64; d<<=1){
    float oA=__shfl_up(incA,d,64), oB=__shfl_up(incB,d,64);
    if (lane>=d){ incA+=oA; incB+=oB; }
  }
  float exA=incA-RA.run, exB=incB-RB.run;
  if (lane==0){ csw[0]=0.f; csw[NP]=0.f; }
  const int j0 = lane*4;
  #pragma unroll
  for (int k=0;k<4;k++){
    int idx=j0+k+1;
    if (idx<NP){ csw[idx]=exA+RA.cpre[k]; csw[NP+idx]=exB+RB.cpre[k]; }
  }

  // interleaved argmin butterflies (first-min for fwd, last-min for rev)
  #pragma unroll
  for (int d=1; d<64; d<<=1){
    float od; int oj; float ot;
    od=__shfl_xor(RA.bdf,d,64); oj=__shfl_xor(RA.bjf,d,64); ot=__shfl_xor(RA.btf,d,64);
    if (od<RA.bdf || (od==RA.bdf && oj<RA.bjf)){RA.bdf=od;RA.bjf=oj;RA.btf=ot;}
    od=__shfl_xor(RA.bdl,d,64); oj=__shfl_xor(RA.bjl,d,64); ot=__shfl_xor(RA.btl,d,64);
    if (od<RA.bdl || (od==RA.bdl && oj>RA.bjl)){RA.bdl=od;RA.bjl=oj;RA.btl=ot;}
    od=__shfl_xor(RB.bdf,d,64); oj=__shfl_xor(RB.bjf,d,64); ot=__shfl_xor(RB.btf,d,64);
    if (od<RB.bdf || (od==RB.bdf && oj<RB.bjf)){RB.bdf=od;RB.bjf=oj;RB.btf=ot;}
    od=__shfl_xor(RB.bdl,d,64); oj=__shfl_xor(RB.bjl,d,64); ot=__shfl_xor(RB.btl,d,64);
    if (od<RB.bdl || (od==RB.bdl && oj>RB.bjl)){RB.bdl=od;RB.bjl=oj;RB.btl=ot;}
  }

  lds_fence();  // cums/pts visible for cross-lane reads

  const float TotA = csw[nvA-1], TotB = csw[NP+nvB-1];
  float e0A = csw[RA.bjf] + RA.btf*(csw[RA.bjf+1]-csw[RA.bjf]);
  float e1A = (TotA - csw[RA.bjl+1]) + (1.f-RA.btl)*(csw[RA.bjl+1]-csw[RA.bjl]);
  float e0B = csw[NP+RB.bjf] + RB.btf*(csw[NP+RB.bjf+1]-csw[NP+RB.bjf]);
  float e1B = (TotB - csw[NP+RB.bjl+1]) + (1.f-RB.btl)*(csw[NP+RB.bjl+1]-csw[NP+RB.bjl]);

  // timestep phase: 320 tasks = 2 cand x 2 dir x 80 t, exactly 5 full passes
  float a00=0.f,a01=0.f,a10=0.f,a11=0.f;
  #pragma unroll
  for (int p=0;p<5;p++){
    int task = p*64 + lane;
    int cB  = task >= 160;
    int r   = cB ? task-160 : task;
    int dir = r >= TT;
    int t   = dir ? r-TT : r;
    int off = cB ? NP : 0;
    float Tot = cB ? TotB : TotA;
    int nv  = cB ? nvB : nvA;
    float entry = cB ? (dir? e1B : e0B) : (dir? e1A : e0A);
    float ts = entry + tc[t];
    ts = fminf(fmaxf(ts,0.f),Tot);
    float v = dir ? (Tot-ts) : ts;
    const float* cs = csw + off;
    int lo=0, hi=NP;
    #pragma unroll
    for (int s=0;s<8;s++){
      int mid=(lo+hi)>>1;
      float cv = cs[mid];
      bool cond = dir ? (cv>=v) : (cv>v);
      if (cond) hi=mid; else lo=mid+1;
    }
    int jmaxv = nv-2;
    int ia, ib; float tl;
    if (!dir){
      int j = lo-1; j = j<0?0:(j>jmaxv?jmaxv:j);
      tl = (ts - cs[j]) * frcp(fmaxf(cs[j+1]-cs[j], EPS_LEN));
      ia=j; ib=j+1;
    } else {
      int j = nv-1-lo; j = j<0?0:(j>jmaxv?jmaxv:j);
      int l2 = nv-1-j;
      float base = Tot - cs[l2];
      tl = (ts-base)*frcp(fmaxf(cs[l2]-cs[l2-1], EPS_LEN));
      ia=l2; ib=l2-1;
    }
    tl = fminf(fmaxf(tl,0.f),1.f);
    float ax=pxw[off+ia], ay=pyw[off+ia], az=pzw[off+ia];
    float bx=pxw[off+ib], by=pyw[off+ib], bz=pzw[off+ib];
    float prx=ax+tl*(bx-ax), pry=ay+tl*(by-ay), prz=az+tl*(bz-az);
    float dx=pos[t*3+0]-prx, dy=pos[t*3+1]-pry, dz=pos[t*3+2]-prz;
    float dd=fsq(dx*dx+dy*dy+dz*dz);
    bool bd = dir!=0, bc = cB!=0;
    a00 += (!bc && !bd)? dd:0.f;
    a01 += (!bc &&  bd)? dd:0.f;
    a10 += ( bc && !bd)? dd:0.f;
    a11 += ( bc &&  bd)? dd:0.f;
  }
  #pragma unroll
  for (int d=1; d<64; d<<=1){
    a00+=__shfl_xor(a00,d,64);
    a01+=__shfl_xor(a01,d,64);
    a10+=__shfl_xor(a10,d,64);
    a11+=__shfl_xor(a11,d,64);
  }
  if (lane==0){
    float4 cw;
    cw.x = (nvAr>=2)? a00 : INFINITY;
    cw.y = (nvAr>=2)? a01 : INFINITY;
    cw.z = (nvBr>=2)? a10 : INFINITY;
    cw.w = (nvBr>=2)? a11 : INFINITY;
    *(float4*)(cost + nbA*2) = cw;
  }
}

// ---- single-candidate eval (used by winner recompute) — proven R2 path ----
__device__ void eval_write(float* px, float* py, float* pz, float* cums,
                           const float* __restrict__ pos, const float* __restrict__ tcs,
                           const float4* __restrict__ p4, int nv, int wdir,
                           float* __restrict__ out) {
  const int lane = threadIdx.x & 63;
  SegOut R;
  seg_pass(p4, lane, nv, pos[0], pos[1], pos[2], px, py, pz, R);
  float inc = R.run;
  #pragma unroll
  for (int d=1;d<64;d<<=1){ float o=__shfl_up(inc,d,64); if(lane>=d) inc+=o; }
  float excl = inc - R.run;
  if (lane==0) cums[0]=0.f;
  const int j0 = lane*4;
  #pragma unroll
  for (int k=0;k<4;k++){ int idx=j0+k+1; if(idx<NP) cums[idx]=excl+R.cpre[k]; }
  #pragma unroll
  for (int d=1;d<64;d<<=1){
    float od; int oj; float ot;
    od=__shfl_xor(R.bdf,d,64); oj=__shfl_xor(R.bjf,d,64); ot=__shfl_xor(R.btf,d,64);
    if (od<R.bdf || (od==R.bdf && oj<R.bjf)){R.bdf=od;R.bjf=oj;R.btf=ot;}
    od=__shfl_xor(R.bdl,d,64); oj=__shfl_xor(R.bjl,d,64); ot=__shfl_xor(R.btl,d,64);
    if (od<R.bdl || (od==R.bdl && oj>R.bjl)){R.bdl=od;R.bjl=oj;R.btl=ot;}
  }
  lds_fence();
  const float Tot = cums[nv-1];
  float entry;
  if (wdir==0) entry = cums[R.bjf] + R.btf*(cums[R.bjf+1]-cums[R.bjf]);
  else         entry = (Tot - cums[R.bjl+1]) + (1.f-R.btl)*(cums[R.bjl+1]-cums[R.bjl]);
  const int jmaxv = nv-2;
  #pragma unroll
  for (int p=0;p<2;p++){
    int t = p*64 + lane;
    if (t < TT){
      float ts = entry + tcs[t];
      ts = fminf(fmaxf(ts,0.f),Tot);
      float v = wdir ? (Tot-ts) : ts;
      int lo=0, hi=NP;
      #pragma unroll
      for (int s=0;s<8;s++){
        int mid=(lo+hi)>>1;
        float cv = cums[mid];
        bool cond = wdir ? (cv>=v) : (cv>v);
        if (cond) hi=mid; else lo=mid+1;
      }
      int ia, ib; float tl;
      if (!wdir){
        int j = lo-1; j = j<0?0:(j>jmaxv?jmaxv:j);
        tl = (ts - cums[j]) * frcp(fmaxf(cums[j+1]-cums[j], EPS_LEN));
        ia=j; ib=j+1;
      } else {
        int j = nv-1-lo; j = j<0?0:(j>jmaxv?jmaxv:j);
        int l2 = nv-1-j;
        float base = Tot - cums[l2];
        tl = (ts-base)*frcp(fmaxf(cums[l2]-cums[l2-1], EPS_LEN));
        ia=l2; ib=l2-1;
      }
      tl = fminf(fmaxf(tl,0.f),1.f);
      float ax=px[ia], ay=py[ia], az=pz[ia];
      float bx=px[ib], by=py[ib], bz=pz[ib];
      out[t*3+0]=ax+tl*(bx-ax); out[t*3+1]=ay+tl*(by-ay); out[t*3+2]=az+tl*(bz-az);
    }
  }
}

// K1: per-n trajectory cum arc length, one wave per n
__global__ __launch_bounds__(256)
void traj_cs_kernel(const float* __restrict__ traj, float* __restrict__ tcs) {
  const int wid = threadIdx.x>>6, lane = threadIdx.x&63;
  const int n = blockIdx.x*4 + wid;
  const float* p = traj + (size_t)n*TT*3;
  float* o = tcs + (size_t)n*TT;
  float dx=p[(lane+1)*3+0]-p[lane*3+0];
  float dy=p[(lane+1)*3+1]-p[lane*3+1];
  float dz=p[(lane+1)*3+2]-p[lane*3+2];
  float sA = sqrtf(dx*dx+dy*dy+dz*dz);
  float incA = sA;
  #pragma unroll
  for (int d=1;d<64;d<<=1){ float ov=__shfl_up(incA,d,64); if(lane>=d) incA+=ov; }
  o[lane+1] = incA;
  float tot = __shfl(incA, 63, 64);
  float sB = 0.f;
  if (lane<15){
    int t = 64+lane;
    float ex=p[(t+1)*3+0]-p[t*3+0];
    float ey=p[(t+1)*3+1]-p[t*3+1];
    float ez=p[(t+1)*3+2]-p[t*3+2];
    sB = sqrtf(ex*ex+ey*ey+ez*ez);
  }
  float incB = sB;
  #pragma unroll
  for (int d=1;d<64;d<<=1){ float ov=__shfl_up(incB,d,64); if(lane>=d) incB+=ov; }
  if (lane<15) o[65+lane] = tot + incB;
  if (lane==0) o[0] = 0.f;
}

// K3: one wave per n -> argmin over 32 candidates, recompute winner, write out
__global__ __launch_bounds__(256)
void winner_kernel(const float* __restrict__ traj, const float* __restrict__ rp,
                   const void* __restrict__ mask, const float* __restrict__ tcs,
                   const float* __restrict__ cost, float* __restrict__ out) {
  __shared__ float spx[4][NP], spy[4][NP], spz[4][NP], scums[4][NP];
  const int wid = threadIdx.x>>6, lane = threadIdx.x&63;
  const int n = blockIdx.x*4 + wid;
  const float* c = cost + (size_t)n*NBB*2;
  float bc = (lane<NBB*2) ? c[lane] : INFINITY;
  int bi = (lane<NBB*2) ? lane : 64;
  #pragma unroll
  for (int d=1;d<64;d<<=1){
    float oc=__shfl_xor(bc,d,64); int oi=__shfl_xor(bi,d,64);
    if (oc<bc || (oc==bc && oi<bi)){bc=oc;bi=oi;}
  }
  const float* pos = traj + (size_t)n*TT*3;
  float* o = out + (size_t)n*TT*3;
  if (bc == INFINITY){  // no valid candidate: passthrough
    if (lane < 60) ((float4*)o)[lane] = ((const float4*)pos)[lane];
    return;
  }
  int b = bi>>1, dir = bi&1;
  const size_t nbi = (size_t)n*NBB + b;
  int nv = wave_nv(mask, nbi*NP, lane);
  nv = max(nv, 2);
  eval_write(spx[wid],spy[wid],spz[wid],scums[wid],
             pos, tcs+(size_t)n*TT,
             (const float4*)(rp+nbi*NP*3), nv, dir, o);
}

extern "C" void kernel_launch(void* const* d_in, const int* in_sizes, int n_in,
                              void* d_out, int out_size, void* d_ws, size_t ws_size,
                              hipStream_t stream) {
  const float* traj = (const float*)d_in[0];
  const float* rp   = (const float*)d_in[1];
  const void*  mask = d_in[2];
  float* tcs  = (float*)d_ws;                    // N*T floats
  float* cost = tcs + (size_t)NN * TT;           // N*NB*2 floats
  float* out  = (float*)d_out;

  hipLaunchKernelGGL(traj_cs_kernel, dim3(NN/4), dim3(256), 0, stream, traj, tcs);
  hipLaunchKernelGGL(fused_cost_dual, dim3(NN*NBB/8), dim3(256), 0, stream,
                     traj, rp, mask, tcs, cost);
  hipLaunchKernelGGL(winner_kernel, dim3(NN/4), dim3(256), 0, stream,
                     traj, rp, mask, tcs, cost, out);
}

// Round 5
// 39.998 us; speedup vs baseline: 1.0721x; 1.0721x over previous
//
#include <hip/hip_runtime.h>
#include <math.h>

#define NN 1024
#define NBB 16
#define NP 256
#define TT 80
#define EPS_LEN 1e-9f
#define EPS_DD 1e-12f

__device__ __forceinline__ float frcp(float x){ return __builtin_amdgcn_rcpf(x); }
__device__ __forceinline__ float fsq(float x){ return __builtin_amdgcn_sqrtf(x); }

// Wave-synchronous LDS fence (LDS partitioned per wave; no __syncthreads).
__device__ __forceinline__ void lds_fence() {
  __builtin_amdgcn_wave_barrier();
  asm volatile("s_waitcnt lgkmcnt(0)" ::: "memory");
  __builtin_amdgcn_wave_barrier();
}

// n_valid, wave-wide. Mask layout auto-detect: byte[1] of buffer != 0 -> bool
// bytes (mask[0][0][1] true since lengths>=2); int32 layout -> that byte is 0.
__device__ __forceinline__ int wave_nv(const void* mask, size_t base, int lane) {
  bool as_byte = ((const unsigned char*)mask)[1] != 0;
  int nv = 0;
  if (as_byte) {
    uchar4 v = ((const uchar4*)((const unsigned char*)mask + base))[lane];
    nv += __popcll(__ballot(v.x != 0));
    nv += __popcll(__ballot(v.y != 0));
    nv += __popcll(__ballot(v.z != 0));
    nv += __popcll(__ballot(v.w != 0));
  } else {
    int4 v = ((const int4*)((const int*)mask + base))[lane];
    nv += __popcll(__ballot(v.x != 0));
    nv += __popcll(__ballot(v.y != 0));
    nv += __popcll(__ballot(v.z != 0));
    nv += __popcll(__ballot(v.w != 0));
  }
  return nv;
}

// Count of entries in cs[0..255] that are (< v) if STRICT else (<= v).
// Level 1: 16 register coarse values co[k] = cs[16k+15] (cs nondecreasing).
// Level 2: 4 independent ds_read_b128 of the selected 16-entry bucket.
// Exactly equals the count a full binary search over cs[0..255] derives.
template<bool STRICT>
__device__ __forceinline__ int count256(const float* __restrict__ cs,
                                        const float* co, float v){
  int K = 0;
  #pragma unroll
  for (int k=0;k<16;k++) K += STRICT ? (co[k] < v) : (co[k] <= v);
  int base = (K < 16 ? K : 15) * 16;
  const float4* f4 = (const float4*)(cs + base);
  float4 c0=f4[0], c1=f4[1], c2=f4[2], c3=f4[3];
  int r;
  if (STRICT)
    r = (c0.x<v)+(c0.y<v)+(c0.z<v)+(c0.w<v)+(c1.x<v)+(c1.y<v)+(c1.z<v)+(c1.w<v)
      + (c2.x<v)+(c2.y<v)+(c2.z<v)+(c2.w<v)+(c3.x<v)+(c3.y<v)+(c3.z<v)+(c3.w<v);
  else
    r = (c0.x<=v)+(c0.y<=v)+(c0.z<=v)+(c0.w<=v)+(c1.x<=v)+(c1.y<=v)+(c1.z<=v)+(c1.w<=v)
      + (c2.x<=v)+(c2.y<=v)+(c2.z<=v)+(c2.w<=v)+(c3.x<=v)+(c3.y<=v)+(c3.z<=v)+(c3.w<=v);
  return (K >= 16) ? 256 : (base + r);
}

struct SegOut {
  float cpre[4];
  float run;
  float bdf, btf; int bjf;   // first-min (fwd entry)
  float bdl, btl; int bjl;   // last-min  (rev entry)
};

// Per-candidate segment pass: load 256 pts (4/lane), stage to LDS (b128),
// seg lengths + projection of pos[0] + per-lane argmin state.
__device__ __forceinline__ void seg_pass(const float4* __restrict__ p4, int lane, int nv,
                                         float p0x, float p0y, float p0z,
                                         float* __restrict__ px, float* __restrict__ py,
                                         float* __restrict__ pz, SegOut& R) {
  const int j0 = lane * 4;
  float4 A = p4[lane*3+0], B = p4[lane*3+1], C = p4[lane*3+2];
  float x[5], y[5], z[5];
  x[0]=A.x; y[0]=A.y; z[0]=A.z;
  x[1]=A.w; y[1]=B.x; z[1]=B.y;
  x[2]=B.z; y[2]=B.w; z[2]=C.x;
  x[3]=C.y; y[3]=C.z; z[3]=C.w;
  x[4]=__shfl_down(x[0],1,64); y[4]=__shfl_down(y[0],1,64); z[4]=__shfl_down(z[0],1,64);
  ((float4*)px)[lane] = make_float4(x[0],x[1],x[2],x[3]);
  ((float4*)py)[lane] = make_float4(y[0],y[1],y[2],y[3]);
  ((float4*)pz)[lane] = make_float4(z[0],z[1],z[2],z[3]);
  float run = 0.f;
  R.bdf=INFINITY; R.btf=0.f; R.bjf=j0;
  R.bdl=INFINITY; R.btl=0.f; R.bjl=j0;
  #pragma unroll
  for (int k=0;k<4;k++){
    bool valid = (j0+k) < nv-1;
    float vx=x[k+1]-x[k], vy=y[k+1]-y[k], vz=z[k+1]-z[k];
    float n2 = vx*vx+vy*vy+vz*vz;
    float sl = valid ? fmaxf(fsq(n2), EPS_LEN) : 0.f;
    float t = ((p0x-x[k])*vx+(p0y-y[k])*vy+(p0z-z[k])*vz) * frcp(fmaxf(n2,EPS_DD));
    t = fminf(fmaxf(t,0.f),1.f);
    float qx=x[k]+t*vx, qy=y[k]+t*vy, qz=z[k]+t*vz;
    float dx=p0x-qx, dy=p0y-qy, dz=p0z-qz;
    float d2 = valid ? (dx*dx+dy*dy+dz*dz) : INFINITY;
    if (d2 <  R.bdf){R.bdf=d2; R.bjf=j0+k; R.btf=t;}
    if (d2 <= R.bdl){R.bdl=d2; R.bjl=j0+k; R.btl=t;}
    run += sl; R.cpre[k]=run;
  }
  R.run = run;
}

// One wave evaluates one (n,b), both directions fused.
// MODE 0: lane0 writes cost2[0]=fwd, cost2[1]=rev.  MODE 1: write dir=wdir proj.
template<int MODE>
__device__ void eval_wave(float* __restrict__ px, float* __restrict__ py,
                          float* __restrict__ pz, float* __restrict__ cs,
                          const float* __restrict__ pos, const float* __restrict__ tc,
                          const float4* __restrict__ p4, int nv,
                          float* __restrict__ cost2, int wdir, float* __restrict__ out) {
  const int lane = threadIdx.x & 63;
  SegOut R;
  seg_pass(p4, lane, nv, pos[0], pos[1], pos[2], px, py, pz, R);

  // wave exclusive scan of per-lane totals -> cums
  float inc = R.run;
  #pragma unroll
  for (int d=1;d<64;d<<=1){ float o=__shfl_up(inc,d,64); if(lane>=d) inc+=o; }
  float ex = inc - R.run;
  if (lane==0) cs[0]=0.f;
  const int j0 = lane*4;
  #pragma unroll
  for (int k=0;k<4;k++){ int idx=j0+k+1; if(idx<NP) cs[idx]=ex+R.cpre[k]; }

  // coarse table in registers: co[k] = cums[16k+15] (lives on lane 4k+3)
  float cval = ex + R.cpre[2];
  float co[16];
  #pragma unroll
  for (int k=0;k<16;k++) co[k] = __shfl(cval, 4*k+3, 64);

  // argmin butterflies (first-min for fwd, last-min for rev)
  #pragma unroll
  for (int d=1;d<64;d<<=1){
    float od; int oj; float ot;
    od=__shfl_xor(R.bdf,d,64); oj=__shfl_xor(R.bjf,d,64); ot=__shfl_xor(R.btf,d,64);
    if (od<R.bdf || (od==R.bdf && oj<R.bjf)){R.bdf=od;R.bjf=oj;R.btf=ot;}
    od=__shfl_xor(R.bdl,d,64); oj=__shfl_xor(R.bjl,d,64); ot=__shfl_xor(R.btl,d,64);
    if (od<R.bdl || (od==R.bdl && oj>R.bjl)){R.bdl=od;R.bjl=oj;R.btl=ot;}
  }

  // pre-issue pos/tc loads for all passes (independent of the fence)
  constexpr int NPASS = (MODE==0)?3:2;
  float l_tc[NPASS], l_px[NPASS], l_py[NPASS], l_pz[NPASS];
  #pragma unroll
  for (int p=0;p<NPASS;p++){
    int task = p*64 + lane;
    int r = (MODE==0 && task>=TT) ? task-TT : task;
    int t = (r < TT) ? r : 0;
    l_tc[p] = tc[t];
    l_px[p] = pos[t*3+0]; l_py[p] = pos[t*3+1]; l_pz[p] = pos[t*3+2];
  }

  lds_fence();  // cums/pts writes -> visible to cross-lane reads below

  const float Tot = cs[nv-1];
  float e0 = cs[R.bjf] + R.btf*(cs[R.bjf+1]-cs[R.bjf]);
  float e1 = (Tot - cs[R.bjl+1]) + (1.f-R.btl)*(cs[R.bjl+1]-cs[R.bjl]);

  const int jmaxv = nv-2;
  float accf=0.f, accr=0.f;
  #pragma unroll
  for (int p=0;p<NPASS;p++){
    int task = p*64 + lane;
    int dir, t; bool act;
    if (MODE==0){ act = task<2*TT; dir = task>=TT?1:0; t = dir ? task-TT : task; }
    else        { act = task<TT;   dir = wdir;         t = task; }
    float ts = (dir ? e1 : e0) + l_tc[p];
    ts = fminf(fmaxf(ts,0.f),Tot);
    int ia, ib; float tl;
    if (dir){
      float v = Tot - ts;
      int lb = count256<true>(cs, co, v);
      int j = nv-1-lb; j = j<0?0:(j>jmaxv?jmaxv:j);
      int l2 = nv-1-j;
      float base = Tot - cs[l2];
      tl = (ts-base)*frcp(fmaxf(cs[l2]-cs[l2-1], EPS_LEN));
      ia=l2; ib=l2-1;
    } else {
      int ub = count256<false>(cs, co, ts);
      int j = ub-1; j = j<0?0:(j>jmaxv?jmaxv:j);
      tl = (ts - cs[j])*frcp(fmaxf(cs[j+1]-cs[j], EPS_LEN));
      ia=j; ib=j+1;
    }
    tl = fminf(fmaxf(tl,0.f),1.f);
    float ax=px[ia], ay=py[ia], az=pz[ia];
    float bx=px[ib], by=py[ib], bz=pz[ib];
    float prx=ax+tl*(bx-ax), pry=ay+tl*(by-ay), prz=az+tl*(bz-az);
    if (MODE==1){
      if (act){ out[t*3+0]=prx; out[t*3+1]=pry; out[t*3+2]=prz; }
    } else if (act){
      float dx=l_px[p]-prx, dy=l_py[p]-pry, dz=l_pz[p]-prz;
      float dd=fsq(dx*dx+dy*dy+dz*dz);
      if (dir) accr+=dd; else accf+=dd;
    }
  }
  if (MODE==0){
    #pragma unroll
    for (int d=1;d<64;d<<=1){ accf+=__shfl_xor(accf,d,64); accr+=__shfl_xor(accr,d,64); }
    if (lane==0){ cost2[0]=accf; cost2[1]=accr; }
  }
}

// K1: per-n trajectory cum arc length, one wave per n
__global__ __launch_bounds__(256)
void traj_cs_kernel(const float* __restrict__ traj, float* __restrict__ tcs) {
  const int wid = threadIdx.x>>6, lane = threadIdx.x&63;
  const int n = blockIdx.x*4 + wid;
  const float* p = traj + (size_t)n*TT*3;
  float* o = tcs + (size_t)n*TT;
  float dx=p[(lane+1)*3+0]-p[lane*3+0];
  float dy=p[(lane+1)*3+1]-p[lane*3+1];
  float dz=p[(lane+1)*3+2]-p[lane*3+2];
  float sA = sqrtf(dx*dx+dy*dy+dz*dz);
  float incA = sA;
  #pragma unroll
  for (int d=1;d<64;d<<=1){ float ov=__shfl_up(incA,d,64); if(lane>=d) incA+=ov; }
  o[lane+1] = incA;
  float tot = __shfl(incA, 63, 64);
  float sB = 0.f;
  if (lane<15){
    int t = 64+lane;
    float ex=p[(t+1)*3+0]-p[t*3+0];
    float ey=p[(t+1)*3+1]-p[t*3+1];
    float ez=p[(t+1)*3+2]-p[t*3+2];
    sB = sqrtf(ex*ex+ey*ey+ez*ez);
  }
  float incB = sB;
  #pragma unroll
  for (int d=1;d<64;d<<=1){ float ov=__shfl_up(incB,d,64); if(lane>=d) incB+=ov; }
  if (lane<15) o[65+lane] = tot + incB;
  if (lane==0) o[0] = 0.f;
}

// K2: one wave per (n,b) -> both-direction costs
__global__ __launch_bounds__(256)
void fused_cost_kernel(const float* __restrict__ traj, const float* __restrict__ rp,
                       const void* __restrict__ mask, const float* __restrict__ tcs,
                       float* __restrict__ cost) {
  __shared__ float s_px[4][NP], s_py[4][NP], s_pz[4][NP], s_cs[4][NP];
  const int wid = threadIdx.x>>6, lane = threadIdx.x&63;
  const int nb = blockIdx.x*4 + wid;
  const int n = nb / NBB;
  int nvr = wave_nv(mask, (size_t)nb*NP, lane);
  if (nvr < 2){
    if (lane==0){ cost[nb*2+0]=INFINITY; cost[nb*2+1]=INFINITY; }
    return;
  }
  eval_wave<0>(s_px[wid],s_py[wid],s_pz[wid],s_cs[wid],
               traj+(size_t)n*TT*3, tcs+(size_t)n*TT,
               (const float4*)(rp+(size_t)nb*NP*3), nvr,
               cost+(size_t)nb*2, 0, nullptr);
}

// K3: one wave per n -> argmin over 32 candidates, recompute winner, write out
__global__ __launch_bounds__(256)
void winner_kernel(const float* __restrict__ traj, const float* __restrict__ rp,
                   const void* __restrict__ mask, const float* __restrict__ tcs,
                   const float* __restrict__ cost, float* __restrict__ out) {
  __shared__ float s_px[4][NP], s_py[4][NP], s_pz[4][NP], s_cs[4][NP];
  const int wid = threadIdx.x>>6, lane = threadIdx.x&63;
  const int n = blockIdx.x*4 + wid;
  const float* c = cost + (size_t)n*NBB*2;
  float bc = (lane<NBB*2) ? c[lane] : INFINITY;
  int bi = (lane<NBB*2) ? lane : 64;
  #pragma unroll
  for (int d=1;d<64;d<<=1){
    float oc=__shfl_xor(bc,d,64); int oi=__shfl_xor(bi,d,64);
    if (oc<bc || (oc==bc && oi<bi)){bc=oc;bi=oi;}
  }
  const float* pos = traj + (size_t)n*TT*3;
  float* o = out + (size_t)n*TT*3;
  if (bc == INFINITY){  // no valid candidate: passthrough
    if (lane < 60) ((float4*)o)[lane] = ((const float4*)pos)[lane];
    return;
  }
  int b = bi>>1, dir = bi&1;
  const size_t nbi = (size_t)n*NBB + b;
  int nv = wave_nv(mask, nbi*NP, lane);
  nv = max(nv, 2);
  eval_wave<1>(s_px[wid],s_py[wid],s_pz[wid],s_cs[wid],
               pos, tcs+(size_t)n*TT,
               (const float4*)(rp+nbi*NP*3), nv, nullptr, dir, o);
}

extern "C" void kernel_launch(void* const* d_in, const int* in_sizes, int n_in,
                              void* d_out, int out_size, void* d_ws, size_t ws_size,
                              hipStream_t stream) {
  const float* traj = (const float*)d_in[0];
  const float* rp   = (const float*)d_in[1];
  const void*  mask = d_in[2];
  float* tcs  = (float*)d_ws;                    // N*T floats
  float* cost = tcs + (size_t)NN * TT;           // N*NB*2 floats
  float* out  = (float*)d_out;

  hipLaunchKernelGGL(traj_cs_kernel, dim3(NN/4), dim3(256), 0, stream, traj, tcs);
  hipLaunchKernelGGL(fused_cost_kernel, dim3(NN*NBB/4), dim3(256), 0, stream,
                     traj, rp, mask, tcs, cost);
  hipLaunchKernelGGL(winner_kernel, dim3(NN/4), dim3(256), 0, stream,
                     traj, rp, mask, tcs, cost, out);
}

// Round 6
// 36.629 us; speedup vs baseline: 1.1707x; 1.0920x over previous
//
#include <hip/hip_runtime.h>
#include <math.h>

#define NN 1024
#define NBB 16
#define NP 256
#define TT 80
#define EPS_LEN 1e-9f
#define EPS_DD 1e-12f

__device__ __forceinline__ float frcp(float x){ return __builtin_amdgcn_rcpf(x); }
__device__ __forceinline__ float fsq(float x){ return __builtin_amdgcn_sqrtf(x); }
__device__ __forceinline__ float rfl_f(float x){
  return __builtin_bit_cast(float, __builtin_amdgcn_readfirstlane(__builtin_bit_cast(int, x)));
}
__device__ __forceinline__ float rlane_f(float x, int l){
  return __builtin_bit_cast(float, __builtin_amdgcn_readlane(__builtin_bit_cast(int, x), l));
}

// Wave-synchronous LDS fence (LDS partitioned per wave; no __syncthreads).
__device__ __forceinline__ void lds_fence() {
  __builtin_amdgcn_wave_barrier();
  asm volatile("s_waitcnt lgkmcnt(0)" ::: "memory");
  __builtin_amdgcn_wave_barrier();
}

// n_valid, wave-wide. Mask layout auto-detect: byte[1] of buffer != 0 -> bool
// bytes (mask[0][0][1] true since lengths>=2); int32 layout -> that byte is 0.
__device__ __forceinline__ int wave_nv(const void* mask, size_t base, int lane) {
  bool as_byte = ((const unsigned char*)mask)[1] != 0;
  int nv = 0;
  if (as_byte) {
    uchar4 v = ((const uchar4*)((const unsigned char*)mask + base))[lane];
    nv += __popcll(__ballot(v.x != 0));
    nv += __popcll(__ballot(v.y != 0));
    nv += __popcll(__ballot(v.z != 0));
    nv += __popcll(__ballot(v.w != 0));
  } else {
    int4 v = ((const int4*)((const int*)mask + base))[lane];
    nv += __popcll(__ballot(v.x != 0));
    nv += __popcll(__ballot(v.y != 0));
    nv += __popcll(__ballot(v.z != 0));
    nv += __popcll(__ballot(v.w != 0));
  }
  return nv;
}

// Count of entries in cs[0..255] that are (< v) if STRICT else (<= v).
// co[16] are wave-uniform (SGPR) coarse values co[k] = cs[16k+15].
template<bool STRICT>
__device__ __forceinline__ int count256(const float* __restrict__ cs,
                                        const float* co, float v){
  int K = 0;
  #pragma unroll
  for (int k=0;k<16;k++) K += STRICT ? (co[k] < v) : (co[k] <= v);
  int base = (K < 16 ? K : 15) * 16;
  const float4* f4 = (const float4*)(cs + base);
  float4 c0=f4[0], c1=f4[1], c2=f4[2], c3=f4[3];
  int r;
  if (STRICT)
    r = (c0.x<v)+(c0.y<v)+(c0.z<v)+(c0.w<v)+(c1.x<v)+(c1.y<v)+(c1.z<v)+(c1.w<v)
      + (c2.x<v)+(c2.y<v)+(c2.z<v)+(c2.w<v)+(c3.x<v)+(c3.y<v)+(c3.z<v)+(c3.w<v);
  else
    r = (c0.x<=v)+(c0.y<=v)+(c0.z<=v)+(c0.w<=v)+(c1.x<=v)+(c1.y<=v)+(c1.z<=v)+(c1.w<=v)
      + (c2.x<=v)+(c2.y<=v)+(c2.z<=v)+(c2.w<=v)+(c3.x<=v)+(c3.y<=v)+(c3.z<=v)+(c3.w<=v);
  return (K >= 16) ? 256 : (base + r);
}

struct SegOut {
  float cpre[4];
  float run;
  float bdf, btf; int bjf;   // per-lane first-min (fwd)
  float bdl, btl; int bjl;   // per-lane last-min  (rev)
};

// Per-candidate segment pass: load 256 pts (4/lane), stage to LDS (b128),
// seg lengths + projection of pos[0] + per-lane argmin state.
__device__ __forceinline__ void seg_pass(const float4* __restrict__ p4, int lane, int nv,
                                         float p0x, float p0y, float p0z,
                                         float* __restrict__ px, float* __restrict__ py,
                                         float* __restrict__ pz, SegOut& R) {
  const int j0 = lane * 4;
  float4 A = p4[lane*3+0], B = p4[lane*3+1], C = p4[lane*3+2];
  float x[5], y[5], z[5];
  x[0]=A.x; y[0]=A.y; z[0]=A.z;
  x[1]=A.w; y[1]=B.x; z[1]=B.y;
  x[2]=B.z; y[2]=B.w; z[2]=C.x;
  x[3]=C.y; y[3]=C.z; z[3]=C.w;
  x[4]=__shfl_down(x[0],1,64); y[4]=__shfl_down(y[0],1,64); z[4]=__shfl_down(z[0],1,64);
  ((float4*)px)[lane] = make_float4(x[0],x[1],x[2],x[3]);
  ((float4*)py)[lane] = make_float4(y[0],y[1],y[2],y[3]);
  ((float4*)pz)[lane] = make_float4(z[0],z[1],z[2],z[3]);
  float run = 0.f;
  R.bdf=INFINITY; R.btf=0.f; R.bjf=j0;
  R.bdl=INFINITY; R.btl=0.f; R.bjl=j0;
  #pragma unroll
  for (int k=0;k<4;k++){
    bool valid = (j0+k) < nv-1;
    float vx=x[k+1]-x[k], vy=y[k+1]-y[k], vz=z[k+1]-z[k];
    float n2 = vx*vx+vy*vy+vz*vz;
    float sl = valid ? fmaxf(fsq(n2), EPS_LEN) : 0.f;
    float t = ((p0x-x[k])*vx+(p0y-y[k])*vy+(p0z-z[k])*vz) * frcp(fmaxf(n2,EPS_DD));
    t = fminf(fmaxf(t,0.f),1.f);
    float qx=x[k]+t*vx, qy=y[k]+t*vy, qz=z[k]+t*vz;
    float dx=p0x-qx, dy=p0y-qy, dz=p0z-qz;
    float d2 = valid ? (dx*dx+dy*dy+dz*dz) : INFINITY;
    if (d2 <  R.bdf){R.bdf=d2; R.bjf=j0+k; R.btf=t;}
    if (d2 <= R.bdl){R.bdl=d2; R.bjl=j0+k; R.btl=t;}
    run += sl; R.cpre[k]=run;
  }
  R.run = run;
}

// One wave evaluates one (n,b), both directions fused.
// MODE 0: lane0 writes cost2[0]=fwd, cost2[1]=rev.  MODE 1: write dir=wdir proj.
template<int MODE>
__device__ void eval_wave(float* __restrict__ px, float* __restrict__ py,
                          float* __restrict__ pz, float* __restrict__ cs,
                          const float* __restrict__ pos, const float* __restrict__ tc,
                          const float4* __restrict__ p4, int nv,
                          float* __restrict__ cost2, int wdir, float* __restrict__ out) {
  const int lane = threadIdx.x & 63;
  SegOut R;
  seg_pass(p4, lane, nv, pos[0], pos[1], pos[2], px, py, pz, R);

  // wave exclusive scan of per-lane totals
  float inc = R.run;
  #pragma unroll
  for (int d=1;d<64;d<<=1){ float o=__shfl_up(inc,d,64); if(lane>=d) inc+=o; }
  float ex = inc - R.run;
  // aligned single-b128 cums write: cs[4l..4l+3] (bit-identical to old values)
  ((float4*)cs)[lane] = make_float4(ex, ex+R.cpre[0], ex+R.cpre[1], ex+R.cpre[2]);

  // Tot: segs >= nv-1 have len 0, so inclusive total == cs[nv-1]
  const float Tot = rfl_f(__shfl(inc, 63, 64));

  // coarse table -> SGPRs: co[k] = cs[16k+15] (lives on lane 4k+3)
  float cval = ex + R.cpre[2];
  float co[16];
  #pragma unroll
  for (int k=0;k<16;k++) co[k] = rfl_f(__shfl(cval, 4*k+3, 64));

  // global min of d2, then first/last achieving lane via ballot
  float minv = R.bdf;
  #pragma unroll
  for (int d=1;d<64;d<<=1) minv = fminf(minv, __shfl_xor(minv, d, 64));
  unsigned long long mf = __ballot(R.bdf == minv);
  unsigned long long ml = __ballot(R.bdl == minv);
  int lf = __builtin_ctzll(mf);
  int ll = 63 - __builtin_clzll(ml);
  int   jf = __builtin_amdgcn_readlane(R.bjf, lf);
  float tf = rlane_f(R.btf, lf);
  int   jl = __builtin_amdgcn_readlane(R.bjl, ll);
  float tl0 = rlane_f(R.btl, ll);

  // pre-issue tc loads for all passes (independent of the fence)
  constexpr int NPASS = (MODE==0)?3:2;
  float l_tc[NPASS];
  #pragma unroll
  for (int p=0;p<NPASS;p++){
    int task = p*64 + lane;
    int r = (MODE==0 && task>=TT) ? task-TT : task;
    int t = (r < TT) ? r : 0;
    l_tc[p] = tc[t];
  }

  lds_fence();  // cums/pts writes -> visible to cross-lane reads below

  float csjf = cs[jf], csjf1 = cs[jf+1];
  float csjl = cs[jl], csjl1 = cs[jl+1];
  float e0 = csjf + tf*(csjf1-csjf);
  float e1 = (Tot - csjl1) + (1.f-tl0)*(csjl1-csjl);

  const int jmaxv = nv-2;
  float accf=0.f, accr=0.f;
  #pragma unroll
  for (int p=0;p<NPASS;p++){
    int task = p*64 + lane;
    int dir, t; bool act;
    if (MODE==0){ act = task<2*TT; dir = task>=TT?1:0; t = dir ? task-TT : task; }
    else        { act = task<TT;   dir = wdir;         t = task; }
    float ts = (dir ? e1 : e0) + l_tc[p];
    ts = fminf(fmaxf(ts,0.f),Tot);
    int ia, ib; float tl;
    if (dir){
      float v = Tot - ts;
      int lb = count256<true>(cs, co, v);
      int j = nv-1-lb; j = j<0?0:(j>jmaxv?jmaxv:j);
      int l2 = nv-1-j;
      float base = Tot - cs[l2];
      tl = (ts-base)*frcp(fmaxf(cs[l2]-cs[l2-1], EPS_LEN));
      ia=l2; ib=l2-1;
    } else {
      int ub = count256<false>(cs, co, ts);
      int j = ub-1; j = j<0?0:(j>jmaxv?jmaxv:j);
      tl = (ts - cs[j])*frcp(fmaxf(cs[j+1]-cs[j], EPS_LEN));
      ia=j; ib=j+1;
    }
    tl = fminf(fmaxf(tl,0.f),1.f);
    float ax=px[ia], ay=py[ia], az=pz[ia];
    float bx=px[ib], by=py[ib], bz=pz[ib];
    float prx=ax+tl*(bx-ax), pry=ay+tl*(by-ay), prz=az+tl*(bz-az);
    if (MODE==1){
      if (act){ out[t*3+0]=prx; out[t*3+1]=pry; out[t*3+2]=prz; }
    } else if (act){
      float dx=pos[t*3+0]-prx, dy=pos[t*3+1]-pry, dz=pos[t*3+2]-prz;
      float dd=fsq(dx*dx+dy*dy+dz*dz);
      if (dir) accr+=dd; else accf+=dd;
    }
  }
  if (MODE==0){
    #pragma unroll
    for (int d=1;d<64;d<<=1){ accf+=__shfl_xor(accf,d,64); accr+=__shfl_xor(accr,d,64); }
    if (lane==0){ cost2[0]=accf; cost2[1]=accr; }
  }
}

// K1: per-n trajectory cum arc length, one wave per n
__global__ __launch_bounds__(256)
void traj_cs_kernel(const float* __restrict__ traj, float* __restrict__ tcs) {
  const int wid = threadIdx.x>>6, lane = threadIdx.x&63;
  const int n = blockIdx.x*4 + wid;
  const float* p = traj + (size_t)n*TT*3;
  float* o = tcs + (size_t)n*TT;
  float dx=p[(lane+1)*3+0]-p[lane*3+0];
  float dy=p[(lane+1)*3+1]-p[lane*3+1];
  float dz=p[(lane+1)*3+2]-p[lane*3+2];
  float sA = sqrtf(dx*dx+dy*dy+dz*dz);
  float incA = sA;
  #pragma unroll
  for (int d=1;d<64;d<<=1){ float ov=__shfl_up(incA,d,64); if(lane>=d) incA+=ov; }
  o[lane+1] = incA;
  float tot = __shfl(incA, 63, 64);
  float sB = 0.f;
  if (lane<15){
    int t = 64+lane;
    float ex=p[(t+1)*3+0]-p[t*3+0];
    float ey=p[(t+1)*3+1]-p[t*3+1];
    float ez=p[(t+1)*3+2]-p[t*3+2];
    sB = sqrtf(ex*ex+ey*ey+ez*ez);
  }
  float incB = sB;
  #pragma unroll
  for (int d=1;d<64;d<<=1){ float ov=__shfl_up(incB,d,64); if(lane>=d) incB+=ov; }
  if (lane<15) o[65+lane] = tot + incB;
  if (lane==0) o[0] = 0.f;
}

// K2: one wave per (n,b) -> both-direction costs.
// launch_bounds(256,8): force VGPR <= 64 tier -> 8 waves/SIMD residency.
__global__ __launch_bounds__(256, 8)
void fused_cost_kernel(const float* __restrict__ traj, const float* __restrict__ rp,
                       const void* __restrict__ mask, const float* __restrict__ tcs,
                       float* __restrict__ cost) {
  __shared__ float s_px[4][NP], s_py[4][NP], s_pz[4][NP], s_cs[4][NP];
  const int wid = threadIdx.x>>6, lane = threadIdx.x&63;
  const int nb = blockIdx.x*4 + wid;
  const int n = nb / NBB;
  int nvr = wave_nv(mask, (size_t)nb*NP, lane);
  if (nvr < 2){
    if (lane==0){ cost[nb*2+0]=INFINITY; cost[nb*2+1]=INFINITY; }
    return;
  }
  eval_wave<0>(s_px[wid],s_py[wid],s_pz[wid],s_cs[wid],
               traj+(size_t)n*TT*3, tcs+(size_t)n*TT,
               (const float4*)(rp+(size_t)nb*NP*3), nvr,
               cost+(size_t)nb*2, 0, nullptr);
}

// K3: one wave per n -> argmin over 32 candidates, recompute winner, write out
__global__ __launch_bounds__(256)
void winner_kernel(const float* __restrict__ traj, const float* __restrict__ rp,
                   const void* __restrict__ mask, const float* __restrict__ tcs,
                   const float* __restrict__ cost, float* __restrict__ out) {
  __shared__ float s_px[4][NP], s_py[4][NP], s_pz[4][NP], s_cs[4][NP];
  const int wid = threadIdx.x>>6, lane = threadIdx.x&63;
  const int n = blockIdx.x*4 + wid;
  const float* c = cost + (size_t)n*NBB*2;
  float bc = (lane<NBB*2) ? c[lane] : INFINITY;
  int bi = (lane<NBB*2) ? lane : 64;
  #pragma unroll
  for (int d=1;d<64;d<<=1){
    float oc=__shfl_xor(bc,d,64); int oi=__shfl_xor(bi,d,64);
    if (oc<bc || (oc==bc && oi<bi)){bc=oc;bi=oi;}
  }
  const float* pos = traj + (size_t)n*TT*3;
  float* o = out + (size_t)n*TT*3;
  if (bc == INFINITY){  // no valid candidate: passthrough
    if (lane < 60) ((float4*)o)[lane] = ((const float4*)pos)[lane];
    return;
  }
  int b = bi>>1, dir = bi&1;
  const size_t nbi = (size_t)n*NBB + b;
  int nv = wave_nv(mask, nbi*NP, lane);
  nv = max(nv, 2);
  eval_wave<1>(s_px[wid],s_py[wid],s_pz[wid],s_cs[wid],
               pos, tcs+(size_t)n*TT,
               (const float4*)(rp+nbi*NP*3), nv, nullptr, dir, o);
}

extern "C" void kernel_launch(void* const* d_in, const int* in_sizes, int n_in,
                              void* d_out, int out_size, void* d_ws, size_t ws_size,
                              hipStream_t stream) {
  const float* traj = (const float*)d_in[0];
  const float* rp   = (const float*)d_in[1];
  const void*  mask = d_in[2];
  float* tcs  = (float*)d_ws;                    // N*T floats
  float* cost = tcs + (size_t)NN * TT;           // N*NB*2 floats
  float* out  = (float*)d_out;

  hipLaunchKernelGGL(traj_cs_kernel, dim3(NN/4), dim3(256), 0, stream, traj, tcs);
  hipLaunchKernelGGL(fused_cost_kernel, dim3(NN*NBB/4), dim3(256), 0, stream,
                     traj, rp, mask, tcs, cost);
  hipLaunchKernelGGL(winner_kernel, dim3(NN/4), dim3(256), 0, stream,
                     traj, rp, mask, tcs, cost, out);
}